// Round 10
// baseline (209.309 us; speedup 1.0000x reference)
//
#include <hip/hip_runtime.h>
#include <math.h>

// Problem constants (fixed by the reference).
#define Bsz 64
#define Ssz 14
#define Isz 32
#define Csz 10
#define Dsz 16
#define Nsz (Ssz*Ssz*Isz)   // 6272
#define EPSF 1e-9f

#define CH   640            // em chunk: n's per block (== block size); 640 % 32 == 0
#define NCH  10             // chunks; chunk 9 has 512 valid n
#define PST  36             // prm row stride: mean16 | invd16 | K | pad
#define BC   (Bsz*Csz)      // 640
#define CPL  (BC*33)        // partC chunk plane: 21120 floats

// ---------------------------------------------------------------------------
// DPP wave64 sum: row_shr 1/2/4/8 then row_bcast 15/31. Total lands in lane 63.
// VALU-pipe only. Validated rounds 1/3/4/5/6/8/9.
// ---------------------------------------------------------------------------
template<int CTRL, int RMASK>
__device__ __forceinline__ float dpp_add(float x) {
    int y = __builtin_amdgcn_update_dpp(0, __float_as_int(x), CTRL, RMASK, 0xf, true);
    return x + __int_as_float(y);
}
__device__ __forceinline__ float wave_sum64(float x) {
    x = dpp_add<0x111, 0xf>(x);   // row_shr:1
    x = dpp_add<0x112, 0xf>(x);   // row_shr:2
    x = dpp_add<0x114, 0xf>(x);   // row_shr:4
    x = dpp_add<0x118, 0xf>(x);   // row_shr:8
    x = dpp_add<0x142, 0xa>(x);   // row_bcast:15
    x = dpp_add<0x143, 0xc>(x);   // row_bcast:31 -> lane63 = total
    return x;
}

// ---------------------------------------------------------------------------
// m0_kernel: iteration-0 M-step with uniform rr (wgt = act/C). Wave-per-class,
// W16 from global, DPP reduce. NO LDS, NO barriers (r9: spill-free, fast).
// Block (0,0) additionally writes the transposed weight table
// Wt[c][i][16] = w[i][c][16] used by em (coalesced per-lane reads there);
// stream ordering guarantees Wt is complete before em1 launches.
// ---------------------------------------------------------------------------
__global__ __launch_bounds__(640) void m0_kernel(
    const float* __restrict__ pose,     // [B][N][16]
    const float* __restrict__ act,      // [B][N]
    const float* __restrict__ w,        // [I][C][16]
    float* __restrict__ wt,             // [C][I][16] out (5120 floats)
    float* __restrict__ partC)          // [NCH][B*C][33]
{
    const int b = blockIdx.x, chunk = blockIdx.y;
    const int tid = threadIdx.x, wv = tid >> 6, lane = tid & 63;
    const int c = wv;

    if (b == 0 && chunk == 0) {
        for (int t = tid; t < Csz*Isz*Dsz; t += 640) {
            const int cc = t >> 9, rem = t & 511, i = rem >> 4, q = rem & 15;
            wt[t] = w[(i*Csz + cc)*Dsz + q];
        }
    }

    // W[i = lane&31][c] -> registers (4x float4 from L2)
    const float4* wp = reinterpret_cast<const float4*>(
        w + ((size_t)(lane & 31)*Csz + c)*Dsz);
    float4 q0 = wp[0], q1 = wp[1], q2 = wp[2], q3 = wp[3];
    float W16[16] = {q0.x,q0.y,q0.z,q0.w, q1.x,q1.y,q1.z,q1.w,
                     q2.x,q2.y,q2.z,q2.w, q3.x,q3.y,q3.z,q3.w};

    const int base = chunk*CH;
    const float* poseb = pose + (size_t)b*Nsz*Dsz;
    const float* actb  = act  + (size_t)b*Nsz;

    float s0 = 0.f, s1[16], s2[16];
#pragma unroll
    for (int d = 0; d < 16; ++d) { s1[d] = 0.f; s2[d] = 0.f; }

    for (int k = 0; k < CH; k += 64) {
        const int n = base + k + lane;
        if (n < Nsz) {
            const float4* pp = reinterpret_cast<const float4*>(poseb + (size_t)n*Dsz);
            const int hw = n >> 5, wc2 = hw % Ssz, hr2 = hw / Ssz;
            const float chh = (hr2+0.5f)*(1.f/Ssz), cww = (wc2+0.5f)*(1.f/Ssz);
            const float wgt = actb[n]*(1.f/Csz);
            s0 += wgt;
#pragma unroll
            for (int pr = 0; pr < 4; ++pr) {
                const float4 pv = pp[pr];
#pragma unroll
                for (int r = 0; r < 4; ++r) {
                    float vv = pv.x*W16[0*4+r] + pv.y*W16[1*4+r]
                             + pv.z*W16[2*4+r] + pv.w*W16[3*4+r];
                    if (pr == 0 && r == 0) vv += chh;
                    if (pr == 0 && r == 1) vv += cww;
                    const float wvv = wgt*vv;
                    s1[pr*4+r] += wvv;
                    s2[pr*4+r] += wvv*vv;
                }
            }
        }
    }
    s0 = wave_sum64(s0);
#pragma unroll
    for (int d = 0; d < 16; ++d) { s1[d] = wave_sum64(s1[d]); s2[d] = wave_sum64(s2[d]); }
    if (lane == 63) {
        float* pt = partC + (size_t)chunk*CPL + (size_t)(b*Csz + c)*33;
        pt[0] = s0;
#pragma unroll
        for (int d = 0; d < 16; ++d) { pt[1+d] = s1[d]; pt[17+d] = s2[d]; }
    }
}

// ---------------------------------------------------------------------------
// em_kernel: r9 body minus the W LDS. E reads W per-thread from the transposed
// global table Wt[c][i][16] (lanes read CONSECUTIVE 16B blocks -> coalesced
// dwordx4, L1-resident 20KB; replaces 160 stride-17 ds_read_b32 per thread).
// No staging loop, one barrier only (rr). M hoists W16 from Wt (coalesced).
// LDS = rr only (25.6 KB). prm via wave-uniform scalar loads from global (r9).
// ---------------------------------------------------------------------------
__global__ __launch_bounds__(640) void em_kernel(
    const float* __restrict__ pose, const float* __restrict__ act,
    const float* __restrict__ wt,       // [C][I][16] transposed weights
    const float* __restrict__ prm,
    float* __restrict__ partC)          // [NCH][B*C][33]
{
    const int b = blockIdx.x, chunk = blockIdx.y;
    const int tid = threadIdx.x, wv = tid >> 6, lane = tid & 63;

    __shared__ float rr[Csz][CH];       // 25600 B

    const int base = chunk*CH;
    const float* poseb = pose + (size_t)b*Nsz*Dsz;

    {   // ---- E phase: one n per thread ----
        const int n = base + tid;
        if (n < Nsz) {
            const float4* pp = reinterpret_cast<const float4*>(poseb + (size_t)n*Dsz);
            float4 a0 = pp[0], a1 = pp[1], a2 = pp[2], a3 = pp[3];
            float p[16] = {a0.x,a0.y,a0.z,a0.w, a1.x,a1.y,a1.z,a1.w,
                           a2.x,a2.y,a2.z,a2.w, a3.x,a3.y,a3.z,a3.w};
            const int i = tid & 31;
            const int hw = n >> 5;
            const int wc = hw % Ssz, hr = hw / Ssz;
            const float chh = (hr+0.5f)*(1.0f/Ssz), cww = (wc+0.5f)*(1.0f/Ssz);
            const float a = act[(size_t)b*Nsz + n];
            float zz[Csz];
#pragma unroll
            for (int c = 0; c < Csz; ++c) {
                // coalesced: lane's 16B block at (c*32 + i)*64B; L1-hot
                const float4* wp4 = reinterpret_cast<const float4*>(
                    wt + ((size_t)c*Isz + i)*Dsz);
                float4 w0 = wp4[0], w1 = wp4[1], w2 = wp4[2], w3 = wp4[3];
                const float W16[16] = {w0.x,w0.y,w0.z,w0.w, w1.x,w1.y,w1.z,w1.w,
                                       w2.x,w2.y,w2.z,w2.w, w3.x,w3.y,w3.z,w3.w};
                const float* __restrict__ pg = prm + (size_t)(b*Csz + c)*PST; // uniform -> s_load
                float quad = 0.f;
#pragma unroll
                for (int pr = 0; pr < 4; ++pr) {
#pragma unroll
                    for (int r = 0; r < 4; ++r) {
                        float vv = p[pr*4+0]*W16[0*4+r] + p[pr*4+1]*W16[1*4+r]
                                 + p[pr*4+2]*W16[2*4+r] + p[pr*4+3]*W16[3*4+r];
                        if (pr == 0 && r == 0) vv += chh;
                        if (pr == 0 && r == 1) vv += cww;
                        const int d = pr*4 + r;
                        const float dv = vv - pg[d];
                        quad += dv*dv*pg[16+d];
                    }
                }
                zz[c] = pg[32] - quad;
            }
            float zmax = zz[0];
#pragma unroll
            for (int c = 1; c < Csz; ++c) zmax = fmaxf(zmax, zz[c]);
            float zsum = 0.f;
#pragma unroll
            for (int c = 0; c < Csz; ++c) { zz[c] = __expf(zz[c] - zmax); zsum += zz[c]; }
            const float sc = __fdividef(a, zsum);
#pragma unroll
            for (int c = 0; c < Csz; ++c) rr[c][tid] = zz[c]*sc;
        }
    }
    __syncthreads();

    // ---- M phase: wave = class; W16 from Wt (coalesced, i = lane&31) ----
    const int c = wv;
    const float4* wp4 = reinterpret_cast<const float4*>(
        wt + ((size_t)c*Isz + (lane & 31))*Dsz);
    float4 q0 = wp4[0], q1 = wp4[1], q2 = wp4[2], q3 = wp4[3];
    float W16[16] = {q0.x,q0.y,q0.z,q0.w, q1.x,q1.y,q1.z,q1.w,
                     q2.x,q2.y,q2.z,q2.w, q3.x,q3.y,q3.z,q3.w};

    float s0 = 0.f, s1[16], s2[16];
#pragma unroll
    for (int d = 0; d < 16; ++d) { s1[d] = 0.f; s2[d] = 0.f; }

    for (int k = 0; k < CH; k += 64) {
        const int nl = k + lane;
        const int n = base + nl;
        if (n < Nsz) {
            const float4* pp = reinterpret_cast<const float4*>(poseb + (size_t)n*Dsz);
            const int hw = n >> 5;
            const int wc2 = hw % Ssz, hr2 = hw / Ssz;
            const float chh = (hr2+0.5f)*(1.0f/Ssz), cww = (wc2+0.5f)*(1.0f/Ssz);
            const float wgt = rr[c][nl];
            s0 += wgt;
#pragma unroll
            for (int pr = 0; pr < 4; ++pr) {
                const float4 pv = pp[pr];
#pragma unroll
                for (int r = 0; r < 4; ++r) {
                    float vv = pv.x*W16[0*4+r] + pv.y*W16[1*4+r]
                             + pv.z*W16[2*4+r] + pv.w*W16[3*4+r];
                    if (pr == 0 && r == 0) vv += chh;
                    if (pr == 0 && r == 1) vv += cww;
                    const float wvv = wgt*vv;
                    s1[pr*4+r] += wvv;
                    s2[pr*4+r] += wvv*vv;
                }
            }
        }
    }
    s0 = wave_sum64(s0);
#pragma unroll
    for (int d = 0; d < 16; ++d) { s1[d] = wave_sum64(s1[d]); s2[d] = wave_sum64(s2[d]); }
    if (lane == 63) {
        float* pt = partC + (size_t)chunk*CPL + (size_t)(b*Csz + c)*33;
        pt[0] = s0;
#pragma unroll
        for (int d = 0; d < 16; ++d) { pt[1+d] = s1[d]; pt[17+d] = s2[d]; }
    }
}

// ---------------------------------------------------------------------------
// fin_kernel: ONE wave per (b,c) -- 640 blocks. Lane j<33 sums partC[ch][bc][j]
// over 10 chunks (coalesced 33-float rows); shuffles compute mean/var; writes
// prm (mid iterations) or outputs (final). (r9-passing, verbatim.)
// ---------------------------------------------------------------------------
__global__ __launch_bounds__(64) void fin_kernel(
    const float* __restrict__ partC, const float* __restrict__ beta_v,
    const float* __restrict__ beta_a, float* __restrict__ prmOut,
    float* __restrict__ out, float inv_temp)
{
    const int bc = blockIdx.x;          // b*Csz + c
    const int c = bc % Csz;
    const int j = threadIdx.x;

    float S = 0.f;
    if (j < 33) {
        const float* pb = partC + (size_t)bc*33 + j;
#pragma unroll
        for (int ch = 0; ch < NCH; ++ch) S += pb[(size_t)ch*CPL];
    }
    const float S0 = __shfl(S, 0);
    const float rS0 = 1.f / S0;

    // lanes 1..16 own d = j-1
    const int src = (j >= 1 && j <= 16) ? (16 + j) : 0;   // S2 lane for this d
    const float S2d = __shfl(S, src);
    float mn = 0.f, lg = 0.f, iv = 0.f;
    if (j >= 1 && j <= 16) {
        mn = S * rS0;
        const float var = fmaxf(S2d * rS0 - mn*mn, 0.f);
        iv = 1.f/(2.f*var + EPSF);
        lg = __logf(sqrtf(var) + EPSF);
    }
    // wave-reduce sumlog (only lanes 1..16 nonzero)
    float sumlog = lg;
#pragma unroll
    for (int m = 32; m >= 1; m >>= 1) sumlog += __shfl_xor(sumlog, m);

    if (out) {
        if (j >= 1 && j <= 16) out[(size_t)bc*Dsz + (j-1)] = mn;
        if (j == 0) {
            const float cost = S0*(16.f*beta_v[c] + sumlog);
            out[(size_t)Bsz*Csz*Dsz + bc] = 1.f/(1.f + __expf(-inv_temp*(beta_a[c] - cost)));
        }
    } else {
        float* o = prmOut + (size_t)bc*PST;
        if (j >= 1 && j <= 16) { o[j-1] = mn; o[16 + (j-1)] = iv; }
        if (j == 0) {
            const float cost = S0*(16.f*beta_v[c] + sumlog);
            const float oact = 1.f/(1.f + __expf(-inv_temp*(beta_a[c] - cost)));
            o[32] = __logf(oact + EPSF) - sumlog;
        }
    }
}

// ---------------------------------------------------------------------------
// 6 dispatches, no memset: m0(+Wt build) -> fin0 -> em1 -> fin1 -> em2 -> fin2.
// Workspace: partC 211200 fl + prmA/prmB 23040 fl + Wt 5120 fl = 1.05 MB.
// ---------------------------------------------------------------------------
extern "C" void kernel_launch(void* const* d_in, const int* in_sizes, int n_in,
                              void* d_out, int out_size, void* d_ws, size_t ws_size,
                              hipStream_t stream)
{
    (void)in_sizes; (void)n_in; (void)out_size; (void)ws_size;
    const float* pose = (const float*)d_in[0];
    const float* act  = (const float*)d_in[1];
    const float* w    = (const float*)d_in[2];
    const float* bv   = (const float*)d_in[3];
    const float* ba   = (const float*)d_in[4];
    float* out = (float*)d_out;

    float* partC = (float*)d_ws;                       // [10][640][33]
    float* prmA  = partC + (size_t)NCH*CPL;            // [640][36]
    float* prmB  = prmA + (size_t)BC*PST;              // [640][36]
    float* wtT   = prmB + (size_t)BC*PST;              // [10][32][16]

    m0_kernel <<<dim3(Bsz, NCH), 640, 0, stream>>>(pose, act, w, wtT, partC);
    fin_kernel<<<BC,              64, 0, stream>>>(partC, bv, ba, prmA, nullptr, 1.0f);
    em_kernel <<<dim3(Bsz, NCH), 640, 0, stream>>>(pose, act, wtT, prmA, partC);
    fin_kernel<<<BC,              64, 0, stream>>>(partC, bv, ba, prmB, nullptr, 2.0f);
    em_kernel <<<dim3(Bsz, NCH), 640, 0, stream>>>(pose, act, wtT, prmB, partC);
    fin_kernel<<<BC,              64, 0, stream>>>(partC, bv, ba, nullptr, out, 3.0f);
}